// Round 5
// baseline (294.548 us; speedup 1.0000x reference)
//
#include <hip/hip_runtime.h>

// SplineCNN on MI355X — aggregate-before-GEMM restructure.
//
// R0-R3 evidence: the old hw-gather (scatter from a 25MB tensor) is latency-
// bound at ~40us and invariant to bytes/lines/instructions/pipelining; kernel
// boundary release/acquire defeats cross-dispatch L2 locality. Fix: reorder
// the math. s[n,k,c] = sum_{m in N(n)} basis_k(n,m) h[m,c] gathers from h
// (64KB/batch fp16) which is STAGED IN LDS -> per-edge reads are ds_read_u16
// (no memory latency). Then a dense streaming GEMM per layer:
//   out = relu( [s/deg | h] @ [w; root] + bias )  with K = 10*Cin, N = 64.
// Preprocess sorts each row's edge list by quadrant (kx0,ky0 in {0,1}^2) so
// the gather inner loops have compile-time accumulator targets (no branches,
// no runtime-indexed registers). Layer 0 (Cin=128) splits channels across 2
// blocks per batch-slice so the LDS h-tile stays 64KB.
// All tensors fp16 (fp32 accumulate in gather + MFMA); layer-2 GEMM epilogue
// fuses global max-pool via uint-bitcast atomicMax (relu >= 0).

#define B_   32
#define N_   512
#define F_   64
#define CAP  128          // max neighbors per node (mean ~31; P(>128) ~ 18 sigma)

typedef float f32x4 __attribute__((ext_vector_type(4)));
typedef _Float16 f16x8 __attribute__((ext_vector_type(8)));
typedef _Float16 f16x2 __attribute__((ext_vector_type(2)));

// ---------------- preprocess: quadrant-sorted edge lists ----------------
// edge record: float4 { bitcast(m), fx, fy, 1.0 }, sorted by quad = kx0 + 2*ky0.
// cnt4[row] = per-quadrant counts; deginv = 1/clip(deg,1).
// Blocks 0..2047 also zero the pooled-max buffer.
__global__ __launch_bounds__(512) void preprocess_kernel(
    const float* __restrict__ adj, const float* __restrict__ coord,
    float4* __restrict__ edge, int4* __restrict__ cnt4,
    float* __restrict__ deginv, unsigned int* __restrict__ gmax) {
  int row = blockIdx.x;          // b*N + n
  int b = row >> 9;
  int tid = threadIdx.x;         // == m
  int lane = tid & 63, wave = tid >> 6;
  if (row < B_ * F_ && tid == 0) gmax[row] = 0u;
  __shared__ int wc[8][4];
  float a = adj[(size_t)row * N_ + tid];
  bool flag = (a != 0.0f);
  float cxn = coord[(size_t)row * 2 + 0];
  float cyn = coord[(size_t)row * 2 + 1];
  float cxm = coord[(size_t)(b * N_ + tid) * 2 + 0];
  float cym = coord[(size_t)(b * N_ + tid) * 2 + 1];
  float vx = (cxm - cxn + 1.0f);        // = u*2 (K-1 = 2, u in [0,1])
  float vy = (cym - cyn + 1.0f);
  float i0x = fminf(fmaxf(floorf(vx), 0.0f), 1.0f);
  float i0y = fminf(fmaxf(floorf(vy), 0.0f), 1.0f);
  float fx = vx - i0x, fy = vy - i0y;
  int quad = (int)i0x + 2 * (int)i0y;   // 0..3
  unsigned long long bq0 = __ballot(flag && quad == 0);
  unsigned long long bq1 = __ballot(flag && quad == 1);
  unsigned long long bq2 = __ballot(flag && quad == 2);
  unsigned long long bq3 = __ballot(flag && quad == 3);
  if (lane == 0) {
    wc[wave][0] = __popcll(bq0); wc[wave][1] = __popcll(bq1);
    wc[wave][2] = __popcll(bq2); wc[wave][3] = __popcll(bq3);
  }
  __syncthreads();
  int qt0 = 0, qt1 = 0, qt2 = 0, qt3 = 0;
  #pragma unroll
  for (int w2 = 0; w2 < 8; ++w2) {
    qt0 += wc[w2][0]; qt1 += wc[w2][1]; qt2 += wc[w2][2]; qt3 += wc[w2][3];
  }
  if (flag) {
    int off = 0;
    if (quad > 0) off += qt0;
    if (quad > 1) off += qt1;
    if (quad > 2) off += qt2;
    #pragma unroll
    for (int w2 = 0; w2 < 8; ++w2)
      if (w2 < wave) off += wc[w2][quad];
    unsigned long long myb = (quad == 0) ? bq0 : (quad == 1) ? bq1
                           : (quad == 2) ? bq2 : bq3;
    off += __popcll(myb & ((1ULL << lane) - 1ULL));
    if (off < CAP)
      edge[(size_t)row * CAP + off] =
          make_float4(__int_as_float(tid), fx, fy, 1.0f);
  }
  if (tid == 0) {
    int rem = CAP;
    int c0 = min(qt0, rem); rem -= c0;
    int c1 = min(qt1, rem); rem -= c1;
    int c2 = min(qt2, rem); rem -= c2;
    int c3 = min(qt3, rem);
    cnt4[row] = make_int4(c0, c1, c2, c3);
    int total = qt0 + qt1 + qt2 + qt3;
    deginv[row] = 1.0f / (float)(total > 0 ? total : 1);
  }
}

// ---- pack all 3 layers' [w(9 slices); root] -> Wt fp16 [64 f][KP = 10*Cin] ----
__global__ void packw3_kernel(
    const float* __restrict__ w0, const float* __restrict__ root0,
    const float* __restrict__ w1, const float* __restrict__ root1,
    const float* __restrict__ w2, const float* __restrict__ root2,
    _Float16* __restrict__ wt0, _Float16* __restrict__ wt1,
    _Float16* __restrict__ wt2) {
  int idx = blockIdx.x * blockDim.x + threadIdx.x;
  const int S0 = 64 * 1280, S1 = 64 * 640;
  const float *w, *root; _Float16* wt; int KP, CIN, r;
  if (idx < S0)            { w = w0; root = root0; wt = wt0; KP = 1280; CIN = 128; r = idx; }
  else if (idx < S0 + S1)  { w = w1; root = root1; wt = wt1; KP = 640;  CIN = 64;  r = idx - S0; }
  else if (idx < S0 + 2*S1){ w = w2; root = root2; wt = wt2; KP = 640;  CIN = 64;  r = idx - S0 - S1; }
  else return;
  int f = r / KP, k = r - f * KP;
  int ks = k / CIN, c = k - ks * CIN;
  float v = (ks < 9) ? w[((size_t)ks * CIN + c) * F_ + f]
                     : root[(size_t)c * F_ + f];
  wt[(size_t)f * KP + k] = (_Float16)v;
}

// ---------------- gather: s'[row, k*CIN + c] = deginv * sum basis_k * h[m,c] ----------------
// Grid: 32 batches x 8 row-groups x (CIN/64) channel-chunks; 1024 thr = 16 waves,
// each wave 4 rows. h chunk [512][64] fp16 staged in LDS (64 KB). Per edge:
// broadcast float4 record + 1 conflict-free ds_read_u16 per lane + 10 VALU.
// Quadrant-sorted runs -> static accumulator targets. Root column = h passthrough.
__global__ __launch_bounds__(1024) void gather_kernel(
    const float* __restrict__ x0,        // layer-0 source (fp32 [.,128]) or null
    const _Float16* __restrict__ hin,    // layer-1/2 source (fp16 [.,64]) or null
    const float4* __restrict__ edge, const int4* __restrict__ cnt4,
    const float* __restrict__ deginv,
    _Float16* __restrict__ sp,           // [16384][KP]
    int KP, int CIN, int chb) {
  __shared__ __attribute__((aligned(16))) _Float16 hs[512 * 64];  // 64 KB
  int tid = threadIdx.x;
  int ch = blockIdx.x & ((1 << chb) - 1);
  int t = blockIdx.x >> chb;
  int b = t >> 3, rg = t & 7;
  if (x0) {
    const float* xb = x0 + (size_t)b * 512 * 128 + (ch << 6);
    for (int i = tid; i < 512 * 32; i += 1024) {
      int rw = i >> 5, d = (i & 31) * 2;
      float2 v = *(const float2*)(xb + (size_t)rw * 128 + d);
      f16x2 hp; hp[0] = (_Float16)v.x; hp[1] = (_Float16)v.y;
      ((unsigned*)hs)[i] = __builtin_bit_cast(unsigned, hp);
    }
  } else {
    const uint4* hb4 = (const uint4*)(hin + (size_t)b * 512 * 64);
    for (int i = tid; i < 4096; i += 1024) ((uint4*)hs)[i] = hb4[i];
  }
  __syncthreads();
  int wave = tid >> 6, lane = tid & 63;
  for (int rr = 0; rr < 4; ++rr) {
    int n = (rg << 6) + (wave << 2) + rr;     // row within batch
    int row = (b << 9) + n;
    int4 c4 = cnt4[row];
    float di = deginv[row];
    const float4* ep = edge + (size_t)row * CAP;
    float a00 = 0, a01 = 0, a02 = 0, a10 = 0, a11 = 0, a12 = 0,
          a20 = 0, a21 = 0, a22 = 0;
    int e1 = c4.x, e2 = e1 + c4.y, e3 = e2 + c4.z, e4 = e3 + c4.w;

#define EDGE_BODY(E, T00, T01, T10, T11) {                  \
    float4 er = ep[E];                                      \
    int m = __float_as_int(er.x);                           \
    float hv = (float)hs[(m << 6) + lane];                  \
    float fx = er.y, fy = er.z;                             \
    float gx = 1.0f - fx, gy = 1.0f - fy;                   \
    T00 += (gx * gy) * hv; T01 += (gx * fy) * hv;           \
    T10 += (fx * gy) * hv; T11 += (fx * fy) * hv; }

    #pragma unroll 4
    for (int e = 0; e < e1; ++e) EDGE_BODY(e, a00, a01, a10, a11)   // kx0=0,ky0=0
    #pragma unroll 4
    for (int e = e1; e < e2; ++e) EDGE_BODY(e, a10, a11, a20, a21)  // kx0=1,ky0=0
    #pragma unroll 4
    for (int e = e2; e < e3; ++e) EDGE_BODY(e, a01, a02, a11, a12)  // kx0=0,ky0=1
    #pragma unroll 4
    for (int e = e3; e < e4; ++e) EDGE_BODY(e, a11, a12, a21, a22)  // kx0=1,ky0=1
#undef EDGE_BODY

    // k = kx*3 + ky (matches reference reshape); columns k*CIN + ch*64 + lane
    _Float16* sr = sp + (size_t)row * KP + (ch << 6) + lane;
    sr[0]              = (_Float16)(a00 * di);
    sr[(size_t)1*CIN]  = (_Float16)(a01 * di);
    sr[(size_t)2*CIN]  = (_Float16)(a02 * di);
    sr[(size_t)3*CIN]  = (_Float16)(a10 * di);
    sr[(size_t)4*CIN]  = (_Float16)(a11 * di);
    sr[(size_t)5*CIN]  = (_Float16)(a12 * di);
    sr[(size_t)6*CIN]  = (_Float16)(a20 * di);
    sr[(size_t)7*CIN]  = (_Float16)(a21 * di);
    sr[(size_t)8*CIN]  = (_Float16)(a22 * di);
    sr[(size_t)9*CIN]  = hs[(n << 6) + lane];   // root column (passthrough fp16)
  }
}

// ---------------- dense GEMM: out[m,f] = relu( A[m,:]@Wt[f,:] + bias[f] ) ----------------
// A fp16 [16384][KP], Wt fp16 [64][KP]. M-tile 64 (grid 256), 256 thr = 4 waves,
// wave owns 16 rows x 64 cols, 16x16x32 f16 MFMA. Double-buffered LDS with
// issue-early/write-late staging (T14). Epilogue: fp16 h-out and/or fused
// max-pool (atomicMax on uint bits, relu >= 0).
#define GBK  64
#define GLDK 72
__global__ __launch_bounds__(256) void gemm_s_kernel(
    const _Float16* __restrict__ A, const _Float16* __restrict__ Wt,
    const float* __restrict__ bias, _Float16* __restrict__ hout,
    unsigned int* __restrict__ gmax, int KP) {
  __shared__ __attribute__((aligned(16))) _Float16 As[2][64 * GLDK];
  __shared__ __attribute__((aligned(16))) _Float16 Ws[2][64 * GLDK];
  int bm = blockIdx.x << 6;
  int tid = threadIdx.x, wave = tid >> 6, lane = tid & 63;
  int lr = lane & 15, quad = lane >> 4;
  int srow = tid >> 3, sck = (tid & 7) * 8;       // staging: rows srow, srow+32
  const size_t aoff = (size_t)(bm + srow) * KP + sck;
  const size_t woff = (size_t)srow * KP + sck;

  f32x4 acc[4] = {};
  // stage step 0 directly
  {
    *(float4*)&As[0][srow * GLDK + sck]        = *(const float4*)&A[aoff];
    *(float4*)&As[0][(srow + 32) * GLDK + sck] = *(const float4*)&A[aoff + (size_t)32 * KP];
    *(float4*)&Ws[0][srow * GLDK + sck]        = *(const float4*)&Wt[woff];
    *(float4*)&Ws[0][(srow + 32) * GLDK + sck] = *(const float4*)&Wt[woff + (size_t)32 * KP];
  }
  int S = KP / GBK, cur = 0;
  float4 pa0, pa1, pw0, pw1;
  for (int s = 0; s < S; ++s) {
    if (s + 1 < S) {                 // issue next tile's loads (no wait)
      int k0 = (s + 1) * GBK;
      pa0 = *(const float4*)&A[aoff + k0];
      pa1 = *(const float4*)&A[aoff + (size_t)32 * KP + k0];
      pw0 = *(const float4*)&Wt[woff + k0];
      pw1 = *(const float4*)&Wt[woff + (size_t)32 * KP + k0];
    }
    __syncthreads();                 // buf[cur] ready for all waves
    #pragma unroll
    for (int kk = 0; kk < GBK; kk += 32) {
      f16x8 af = *(const f16x8*)&As[cur][(16 * wave + lr) * GLDK + kk + quad * 8];
      #pragma unroll
      for (int j = 0; j < 4; ++j) {
        f16x8 bf = *(const f16x8*)&Ws[cur][(16 * j + lr) * GLDK + kk + quad * 8];
        acc[j] = __builtin_amdgcn_mfma_f32_16x16x32_f16(af, bf, acc[j], 0, 0, 0);
      }
    }
    if (s + 1 < S) {                 // write-late into the other buffer
      int nb = cur ^ 1;
      *(float4*)&As[nb][srow * GLDK + sck]        = pa0;
      *(float4*)&As[nb][(srow + 32) * GLDK + sck] = pa1;
      *(float4*)&Ws[nb][srow * GLDK + sck]        = pw0;
      *(float4*)&Ws[nb][(srow + 32) * GLDK + sck] = pw1;
    }
    cur ^= 1;
  }
  // epilogue: C layout col = lane&15, row = quad*4 + r (verified)
  int b = bm >> 9;
  #pragma unroll
  for (int j = 0; j < 4; ++j) {
    int f = 16 * j + lr;
    float bs = bias[f];
    float vmax = 0.0f;
    #pragma unroll
    for (int r = 0; r < 4; ++r) {
      int m = bm + (wave << 4) + (quad << 2) + r;
      float v = fmaxf(acc[j][r] + bs, 0.0f);
      if (hout) hout[(size_t)m * F_ + f] = (_Float16)v;
      vmax = fmaxf(vmax, v);
    }
    if (gmax) atomicMax(&gmax[(b << 6) + f], __float_as_uint(vmax));
  }
}

// ---------------- FC from pooled features ----------------
__global__ __launch_bounds__(64) void fc_kernel(
    const float* __restrict__ g, const float* __restrict__ fcw,
    const float* __restrict__ fcb, float* __restrict__ out) {
  int b = blockIdx.x;
  int f = threadIdx.x;
  __shared__ float gs[64];
  gs[f] = g[b * F_ + f];
  __syncthreads();
  if (f < 10) {
    float s = fcb[f];
    #pragma unroll
    for (int c = 0; c < 64; ++c) s += gs[c] * fcw[c * 10 + f];
    out[b * 10 + f] = s;
  }
}

extern "C" void kernel_launch(void* const* d_in, const int* in_sizes, int n_in,
                              void* d_out, int out_size, void* d_ws, size_t ws_size,
                              hipStream_t stream) {
  const float* x     = (const float*)d_in[0];
  const float* coord = (const float*)d_in[1];
  const float* adj   = (const float*)d_in[2];
  const float* w0    = (const float*)d_in[3];
  const float* root0 = (const float*)d_in[4];
  const float* b0    = (const float*)d_in[5];
  const float* w1    = (const float*)d_in[6];
  const float* root1 = (const float*)d_in[7];
  const float* b1    = (const float*)d_in[8];
  const float* w2    = (const float*)d_in[9];
  const float* root2 = (const float*)d_in[10];
  const float* b2    = (const float*)d_in[11];
  const float* fcw   = (const float*)d_in[12];
  const float* fcb   = (const float*)d_in[13];
  float* out = (float*)d_out;

  char* ws = (char*)d_ws;
  size_t off = 0;
  auto alloc = [&](size_t bytes) {
    void* p = ws + off;
    off = (off + bytes + 255) & ~(size_t)255;
    return p;
  };
  const int R = B_ * N_;  // 16384
  float4* edge    = (float4*)alloc((size_t)R * CAP * 16);
  int4*   cnt4    = (int4*)  alloc((size_t)R * 16);
  float*  deginv  = (float*) alloc((size_t)R * 4);
  _Float16* wt0   = (_Float16*)alloc((size_t)64 * 1280 * 2);
  _Float16* wt1   = (_Float16*)alloc((size_t)64 * 640 * 2);
  _Float16* wt2   = (_Float16*)alloc((size_t)64 * 640 * 2);
  _Float16* sp    = (_Float16*)alloc((size_t)R * 1280 * 2);   // s' (max K)
  _Float16* hA    = (_Float16*)alloc((size_t)R * 64 * 2);
  _Float16* hB    = (_Float16*)alloc((size_t)R * 64 * 2);
  unsigned int* gmax = (unsigned int*)alloc((size_t)B_ * F_ * 4);

  preprocess_kernel<<<R, 512, 0, stream>>>(adj, coord, edge, cnt4, deginv, gmax);
  packw3_kernel<<<(64 * (1280 + 640 + 640) + 255) / 256, 256, 0, stream>>>(
      w0, root0, w1, root1, w2, root2, wt0, wt1, wt2);

  // layer 0: Cin=128 (2 channel-chunks/block-slice), K = 1280
  gather_kernel<<<32 * 8 * 2, 1024, 0, stream>>>(x, nullptr, edge, cnt4, deginv,
                                                 sp, 1280, 128, 1);
  gemm_s_kernel<<<R / 64, 256, 0, stream>>>(sp, wt0, b0, hA, nullptr, 1280);

  // layer 1: Cin=64, K = 640
  gather_kernel<<<32 * 8, 1024, 0, stream>>>(nullptr, hA, edge, cnt4, deginv,
                                             sp, 640, 64, 0);
  gemm_s_kernel<<<R / 64, 256, 0, stream>>>(sp, wt1, b1, hB, nullptr, 640);

  // layer 2: Cin=64, K = 640 — fused max-pool
  gather_kernel<<<32 * 8, 1024, 0, stream>>>(nullptr, hB, edge, cnt4, deginv,
                                             sp, 640, 64, 0);
  gemm_s_kernel<<<R / 64, 256, 0, stream>>>(sp, wt2, b2, nullptr, gmax, 640);

  fc_kernel<<<B_, 64, 0, stream>>>((const float*)gmax, fcw, fcb, out);
}

// Round 6
// 239.055 us; speedup vs baseline: 1.2321x; 1.2321x over previous
//
#include <hip/hip_runtime.h>

// SplineCNN on MI355X — aggregate-before-GEMM, L2-direct gather.
//
// Math order: s[n, k*CIN+c] = deginv * sum_{m in N(n)} basis_k(n,m) * h[m,c],
// root column appended -> one dense GEMM per layer:
//   out = relu( [s | h] @ [w; root] + bias ),  K = 10*CIN, N = 64.
// The gather reads h DIRECTLY FROM GLOBAL (L2-resident: h = 2MB fp16, x16 =
// 4MB fp16; per-XCD slice <= 512KB via batch-aligned XCD swizzle). R5 evidence:
// LDS-staging this L2-fit tensor was pure overhead (64KB LDS -> 40% occupancy,
// VALUBusy 41%, 70us). Edge records are staged per-wave into a tiny LDS
// buffer with coalesced loads (R2-proven), hot loop reads them via broadcast
// ds_read_b128. No __syncthreads (wave-private LDS). Quadrant-sorted edge
// lists (preprocess) give compile-time accumulator targets.
// All tensors fp16 (fp32 accumulate in gather + MFMA); layer-2 GEMM epilogue
// fuses global max-pool via uint-bitcast atomicMax (relu >= 0).

#define B_   32
#define N_   512
#define F_   64
#define CAP  128          // max neighbors per node (mean ~31; P(>128) ~ 18 sigma)

typedef float f32x4 __attribute__((ext_vector_type(4)));
typedef _Float16 f16x8 __attribute__((ext_vector_type(8)));
typedef _Float16 f16x2 __attribute__((ext_vector_type(2)));

// ---------------- preprocess: quadrant-sorted edge lists ----------------
// edge record: float4 { bitcast(m), fx, fy, unused }, sorted by quad = kx0+2*ky0.
// cnt4[row] = per-quadrant counts (clamped to CAP); deginv = 1/clip(deg,1).
// Blocks 0..2047 also zero the pooled-max buffer.
__global__ __launch_bounds__(512) void preprocess_kernel(
    const float* __restrict__ adj, const float* __restrict__ coord,
    float4* __restrict__ edge, int4* __restrict__ cnt4,
    float* __restrict__ deginv, unsigned int* __restrict__ gmax) {
  int row = blockIdx.x;          // b*N + n
  int b = row >> 9;
  int tid = threadIdx.x;         // == m
  int lane = tid & 63, wave = tid >> 6;
  if (row < B_ * F_ && tid == 0) gmax[row] = 0u;
  __shared__ int wc[8][4];
  float a = adj[(size_t)row * N_ + tid];
  bool flag = (a != 0.0f);
  float cxn = coord[(size_t)row * 2 + 0];
  float cyn = coord[(size_t)row * 2 + 1];
  float cxm = coord[(size_t)(b * N_ + tid) * 2 + 0];
  float cym = coord[(size_t)(b * N_ + tid) * 2 + 1];
  float vx = (cxm - cxn + 1.0f);        // = u*2 (K-1 = 2, u in [0,1])
  float vy = (cym - cyn + 1.0f);
  float i0x = fminf(fmaxf(floorf(vx), 0.0f), 1.0f);
  float i0y = fminf(fmaxf(floorf(vy), 0.0f), 1.0f);
  float fx = vx - i0x, fy = vy - i0y;
  int quad = (int)i0x + 2 * (int)i0y;   // 0..3
  unsigned long long bq0 = __ballot(flag && quad == 0);
  unsigned long long bq1 = __ballot(flag && quad == 1);
  unsigned long long bq2 = __ballot(flag && quad == 2);
  unsigned long long bq3 = __ballot(flag && quad == 3);
  if (lane == 0) {
    wc[wave][0] = __popcll(bq0); wc[wave][1] = __popcll(bq1);
    wc[wave][2] = __popcll(bq2); wc[wave][3] = __popcll(bq3);
  }
  __syncthreads();
  int qt0 = 0, qt1 = 0, qt2 = 0, qt3 = 0;
  #pragma unroll
  for (int w2 = 0; w2 < 8; ++w2) {
    qt0 += wc[w2][0]; qt1 += wc[w2][1]; qt2 += wc[w2][2]; qt3 += wc[w2][3];
  }
  if (flag) {
    int off = 0;
    if (quad > 0) off += qt0;
    if (quad > 1) off += qt1;
    if (quad > 2) off += qt2;
    #pragma unroll
    for (int w2 = 0; w2 < 8; ++w2)
      if (w2 < wave) off += wc[w2][quad];
    unsigned long long myb = (quad == 0) ? bq0 : (quad == 1) ? bq1
                           : (quad == 2) ? bq2 : bq3;
    off += __popcll(myb & ((1ULL << lane) - 1ULL));
    if (off < CAP)
      edge[(size_t)row * CAP + off] =
          make_float4(__int_as_float(tid), fx, fy, 1.0f);
  }
  if (tid == 0) {
    int rem = CAP;
    int c0 = min(qt0, rem); rem -= c0;
    int c1 = min(qt1, rem); rem -= c1;
    int c2 = min(qt2, rem); rem -= c2;
    int c3 = min(qt3, rem);
    cnt4[row] = make_int4(c0, c1, c2, c3);
    int total = qt0 + qt1 + qt2 + qt3;
    deginv[row] = 1.0f / (float)(total > 0 ? total : 1);
  }
}

// ---------------- x fp32 [16384,128] -> fp16 [16384,128] ----------------
__global__ void convx16_kernel(const float* __restrict__ x, _Float16* __restrict__ hx) {
  int idx = blockIdx.x * blockDim.x + threadIdx.x;     // 4 elems per thread
  if (idx >= B_ * N_ * 32) return;
  float4 v = ((const float4*)x)[idx];
  f16x2 p0, p1;
  p0[0] = (_Float16)v.x; p0[1] = (_Float16)v.y;
  p1[0] = (_Float16)v.z; p1[1] = (_Float16)v.w;
  uint2 u;
  u.x = __builtin_bit_cast(unsigned, p0);
  u.y = __builtin_bit_cast(unsigned, p1);
  ((uint2*)hx)[idx] = u;
}

// ---- pack all 3 layers' [w(9 slices); root] -> Wt fp16 [64 f][KP = 10*Cin] ----
__global__ void packw3_kernel(
    const float* __restrict__ w0, const float* __restrict__ root0,
    const float* __restrict__ w1, const float* __restrict__ root1,
    const float* __restrict__ w2, const float* __restrict__ root2,
    _Float16* __restrict__ wt0, _Float16* __restrict__ wt1,
    _Float16* __restrict__ wt2) {
  int idx = blockIdx.x * blockDim.x + threadIdx.x;
  const int S0 = 64 * 1280, S1 = 64 * 640;
  const float *w, *root; _Float16* wt; int KP, CIN, r;
  if (idx < S0)            { w = w0; root = root0; wt = wt0; KP = 1280; CIN = 128; r = idx; }
  else if (idx < S0 + S1)  { w = w1; root = root1; wt = wt1; KP = 640;  CIN = 64;  r = idx - S0; }
  else if (idx < S0 + 2*S1){ w = w2; root = root2; wt = wt2; KP = 640;  CIN = 64;  r = idx - S0 - S1; }
  else return;
  int f = r / KP, k = r - f * KP;
  int ks = k / CIN, c = k - ks * CIN;
  float v = (ks < 9) ? w[((size_t)ks * CIN + c) * F_ + f]
                     : root[(size_t)c * F_ + f];
  wt[(size_t)f * KP + k] = (_Float16)v;
}

// ---------------- gather: s[row, k*CIN + c] = deginv * sum basis_k * h[m,c] ----------------
// 256 threads = 4 waves, ONE ROW PER WAVE; grid 4096, XCD-swizzled so batch b's
// blocks share an XCD (h slice <=512KB L2-resident). Wave stages its row's edge
// list to LDS (coalesced, <=2 iter), then hot loop: broadcast ds_read_b128
// edge record + contiguous 128/256B global h gather (L2 hit) + 4*CH FMAs.
// Quadrant runs -> static accumulator targets. CH = CIN/64 channels per lane.
template<int CH>
__global__ __launch_bounds__(256, 6) void gather_kernel(
    const _Float16* __restrict__ hsrc,   // [16384][CIN] fp16
    const float4* __restrict__ edge, const int4* __restrict__ cnt4,
    const float* __restrict__ deginv,
    _Float16* __restrict__ sp) {         // [16384][KP]
  const int CIN = 64 * CH, KP = 10 * CIN;
  __shared__ float4 esh[4][CAP];
  int wave = threadIdx.x >> 6, lane = threadIdx.x & 63;
  int xcd = blockIdx.x & 7;
  int j = blockIdx.x >> 3;
  int b = xcd * 4 + (j >> 7);
  int n = ((j & 127) << 2) + wave;          // row within batch
  int row = (b << 9) + n;
  int4 c4 = cnt4[row];
  int e1 = c4.x, e2 = e1 + c4.y, e3 = e2 + c4.z, e4 = e3 + c4.w;
  size_t ebase = (size_t)row * CAP;
  for (int i = lane; i < e4; i += 64)
    esh[wave][i] = edge[ebase + i];         // wave-private region, no barrier
  float di = deginv[row];
  const _Float16* hb = hsrc + (size_t)b * N_ * CIN + lane * CH;

  float acc[3][3][CH];
  #pragma unroll
  for (int kx = 0; kx < 3; ++kx)
    #pragma unroll
    for (int ky = 0; ky < 3; ++ky)
      #pragma unroll
      for (int c = 0; c < CH; ++c) acc[kx][ky][c] = 0.0f;

#define EDGE_BODY(E, KX, KY) {                                        \
    float4 er = esh[wave][E];                                         \
    int m = __float_as_int(er.x);                                     \
    float hv[CH];                                                     \
    if (CH == 1) {                                                    \
      hv[0] = (float)hb[(size_t)m * 64];                              \
    } else {                                                          \
      unsigned u = *(const unsigned*)&hb[(size_t)m * 128];            \
      f16x2 hp = __builtin_bit_cast(f16x2, u);                        \
      hv[0] = (float)hp[0]; hv[CH - 1] = (float)hp[1];                \
    }                                                                 \
    float fx = er.y, fy = er.z;                                       \
    float gx = 1.0f - fx, gy = 1.0f - fy;                             \
    float w00 = gx * gy, w01 = gx * fy, w10 = fx * gy, w11 = fx * fy; \
    _Pragma("unroll")                                                 \
    for (int c = 0; c < CH; ++c) {                                    \
      acc[KX][KY][c]         += w00 * hv[c];                          \
      acc[KX][KY + 1][c]     += w01 * hv[c];                          \
      acc[KX + 1][KY][c]     += w10 * hv[c];                          \
      acc[KX + 1][KY + 1][c] += w11 * hv[c];                          \
    } }

  #pragma unroll 4
  for (int e = 0; e < e1; ++e) EDGE_BODY(e, 0, 0)    // quad0: kx0=0, ky0=0
  #pragma unroll 4
  for (int e = e1; e < e2; ++e) EDGE_BODY(e, 1, 0)   // quad1: kx0=1, ky0=0
  #pragma unroll 4
  for (int e = e2; e < e3; ++e) EDGE_BODY(e, 0, 1)   // quad2: kx0=0, ky0=1
  #pragma unroll 4
  for (int e = e3; e < e4; ++e) EDGE_BODY(e, 1, 1)   // quad3: kx0=1, ky0=1
#undef EDGE_BODY

  // store: k = kx*3 + ky (reference reshape order); cols k*CIN + lane*CH
  _Float16* sr = sp + (size_t)row * KP + lane * CH;
  #pragma unroll
  for (int kx = 0; kx < 3; ++kx)
    #pragma unroll
    for (int ky = 0; ky < 3; ++ky) {
      int k = kx * 3 + ky;
      if (CH == 1) {
        sr[(size_t)k * CIN] = (_Float16)(acc[kx][ky][0] * di);
      } else {
        f16x2 p;
        p[0] = (_Float16)(acc[kx][ky][0] * di);
        p[1] = (_Float16)(acc[kx][ky][CH - 1] * di);
        *(f16x2*)&sr[(size_t)k * CIN] = p;
      }
    }
  // root column: h passthrough
  if (CH == 1) {
    sr[(size_t)9 * CIN] = hb[(size_t)n * 64];
  } else {
    *(unsigned*)&sr[(size_t)9 * CIN] = *(const unsigned*)&hb[(size_t)n * 128];
  }
}

// ---------------- dense GEMM: out[m,f] = relu( A[m,:]@Wt[f,:] + bias[f] ) ----------------
// A fp16 [16384][KP], Wt fp16 [64][KP]. M-tile 64 (grid 256), 256 thr = 4 waves,
// wave owns 16 rows x 64 cols, 16x16x32 f16 MFMA. Double-buffered LDS with
// issue-early/write-late staging (T14). Epilogue: fp16 h-out and/or fused
// max-pool (atomicMax on uint bits, relu >= 0).
#define GBK  64
#define GLDK 72
__global__ __launch_bounds__(256) void gemm_s_kernel(
    const _Float16* __restrict__ A, const _Float16* __restrict__ Wt,
    const float* __restrict__ bias, _Float16* __restrict__ hout,
    unsigned int* __restrict__ gmax, int KP) {
  __shared__ __attribute__((aligned(16))) _Float16 As[2][64 * GLDK];
  __shared__ __attribute__((aligned(16))) _Float16 Ws[2][64 * GLDK];
  int bm = blockIdx.x << 6;
  int tid = threadIdx.x, wave = tid >> 6, lane = tid & 63;
  int lr = lane & 15, quad = lane >> 4;
  int srow = tid >> 3, sck = (tid & 7) * 8;       // staging: rows srow, srow+32
  const size_t aoff = (size_t)(bm + srow) * KP + sck;
  const size_t woff = (size_t)srow * KP + sck;

  f32x4 acc[4] = {};
  // stage step 0 directly
  {
    *(float4*)&As[0][srow * GLDK + sck]        = *(const float4*)&A[aoff];
    *(float4*)&As[0][(srow + 32) * GLDK + sck] = *(const float4*)&A[aoff + (size_t)32 * KP];
    *(float4*)&Ws[0][srow * GLDK + sck]        = *(const float4*)&Wt[woff];
    *(float4*)&Ws[0][(srow + 32) * GLDK + sck] = *(const float4*)&Wt[woff + (size_t)32 * KP];
  }
  int S = KP / GBK, cur = 0;
  float4 pa0, pa1, pw0, pw1;
  for (int s = 0; s < S; ++s) {
    if (s + 1 < S) {                 // issue next tile's loads (no wait)
      int k0 = (s + 1) * GBK;
      pa0 = *(const float4*)&A[aoff + k0];
      pa1 = *(const float4*)&A[aoff + (size_t)32 * KP + k0];
      pw0 = *(const float4*)&Wt[woff + k0];
      pw1 = *(const float4*)&Wt[woff + (size_t)32 * KP + k0];
    }
    __syncthreads();                 // buf[cur] ready for all waves
    #pragma unroll
    for (int kk = 0; kk < GBK; kk += 32) {
      f16x8 af = *(const f16x8*)&As[cur][(16 * wave + lr) * GLDK + kk + quad * 8];
      #pragma unroll
      for (int j = 0; j < 4; ++j) {
        f16x8 bf = *(const f16x8*)&Ws[cur][(16 * j + lr) * GLDK + kk + quad * 8];
        acc[j] = __builtin_amdgcn_mfma_f32_16x16x32_f16(af, bf, acc[j], 0, 0, 0);
      }
    }
    if (s + 1 < S) {                 // write-late into the other buffer
      int nb = cur ^ 1;
      *(float4*)&As[nb][srow * GLDK + sck]        = pa0;
      *(float4*)&As[nb][(srow + 32) * GLDK + sck] = pa1;
      *(float4*)&Ws[nb][srow * GLDK + sck]        = pw0;
      *(float4*)&Ws[nb][(srow + 32) * GLDK + sck] = pw1;
    }
    cur ^= 1;
  }
  // epilogue: C layout col = lane&15, row = quad*4 + r (verified)
  int b = bm >> 9;
  #pragma unroll
  for (int j = 0; j < 4; ++j) {
    int f = 16 * j + lr;
    float bs = bias[f];
    float vmax = 0.0f;
    #pragma unroll
    for (int r = 0; r < 4; ++r) {
      int m = bm + (wave << 4) + (quad << 2) + r;
      float v = fmaxf(acc[j][r] + bs, 0.0f);
      if (hout) hout[(size_t)m * F_ + f] = (_Float16)v;
      vmax = fmaxf(vmax, v);
    }
    if (gmax) atomicMax(&gmax[(b << 6) + f], __float_as_uint(vmax));
  }
}

// ---------------- FC from pooled features ----------------
__global__ __launch_bounds__(64) void fc_kernel(
    const float* __restrict__ g, const float* __restrict__ fcw,
    const float* __restrict__ fcb, float* __restrict__ out) {
  int b = blockIdx.x;
  int f = threadIdx.x;
  __shared__ float gs[64];
  gs[f] = g[b * F_ + f];
  __syncthreads();
  if (f < 10) {
    float s = fcb[f];
    #pragma unroll
    for (int c = 0; c < 64; ++c) s += gs[c] * fcw[c * 10 + f];
    out[b * 10 + f] = s;
  }
}

extern "C" void kernel_launch(void* const* d_in, const int* in_sizes, int n_in,
                              void* d_out, int out_size, void* d_ws, size_t ws_size,
                              hipStream_t stream) {
  const float* x     = (const float*)d_in[0];
  const float* coord = (const float*)d_in[1];
  const float* adj   = (const float*)d_in[2];
  const float* w0    = (const float*)d_in[3];
  const float* root0 = (const float*)d_in[4];
  const float* b0    = (const float*)d_in[5];
  const float* w1    = (const float*)d_in[6];
  const float* root1 = (const float*)d_in[7];
  const float* b1    = (const float*)d_in[8];
  const float* w2    = (const float*)d_in[9];
  const float* root2 = (const float*)d_in[10];
  const float* b2    = (const float*)d_in[11];
  const float* fcw   = (const float*)d_in[12];
  const float* fcb   = (const float*)d_in[13];
  float* out = (float*)d_out;

  char* ws = (char*)d_ws;
  size_t off = 0;
  auto alloc = [&](size_t bytes) {
    void* p = ws + off;
    off = (off + bytes + 255) & ~(size_t)255;
    return p;
  };
  const int R = B_ * N_;  // 16384
  float4* edge    = (float4*)alloc((size_t)R * CAP * 16);
  int4*   cnt4    = (int4*)  alloc((size_t)R * 16);
  float*  deginv  = (float*) alloc((size_t)R * 4);
  _Float16* hx    = (_Float16*)alloc((size_t)R * 128 * 2);   // fp16 x
  _Float16* wt0   = (_Float16*)alloc((size_t)64 * 1280 * 2);
  _Float16* wt1   = (_Float16*)alloc((size_t)64 * 640 * 2);
  _Float16* wt2   = (_Float16*)alloc((size_t)64 * 640 * 2);
  _Float16* sp    = (_Float16*)alloc((size_t)R * 1280 * 2);  // s (max K)
  _Float16* hA    = (_Float16*)alloc((size_t)R * 64 * 2);
  _Float16* hB    = (_Float16*)alloc((size_t)R * 64 * 2);
  unsigned int* gmax = (unsigned int*)alloc((size_t)B_ * F_ * 4);

  preprocess_kernel<<<R, 512, 0, stream>>>(adj, coord, edge, cnt4, deginv, gmax);
  convx16_kernel<<<(R * 32 + 255) / 256, 256, 0, stream>>>(x, hx);
  packw3_kernel<<<(64 * (1280 + 640 + 640) + 255) / 256, 256, 0, stream>>>(
      w0, root0, w1, root1, w2, root2, wt0, wt1, wt2);

  // layer 0: CIN=128, K = 1280
  gather_kernel<2><<<R / 4, 256, 0, stream>>>(hx, edge, cnt4, deginv, sp);
  gemm_s_kernel<<<R / 64, 256, 0, stream>>>(sp, wt0, b0, hA, nullptr, 1280);

  // layer 1: CIN=64, K = 640
  gather_kernel<1><<<R / 4, 256, 0, stream>>>(hA, edge, cnt4, deginv, sp);
  gemm_s_kernel<<<R / 64, 256, 0, stream>>>(sp, wt1, b1, hB, nullptr, 640);

  // layer 2: CIN=64, K = 640 — fused max-pool
  gather_kernel<1><<<R / 4, 256, 0, stream>>>(hB, edge, cnt4, deginv, sp);
  gemm_s_kernel<<<R / 64, 256, 0, stream>>>(sp, wt2, b2, nullptr, gmax, 640);

  fc_kernel<<<B_, 64, 0, stream>>>((const float*)gmax, fcw, fcb, out);
}